// Round 7
// baseline (282.805 us; speedup 1.0000x reference)
//
#include <hip/hip_runtime.h>
#include <hip/hip_bf16.h>
#include <math.h>

#define DIM 128
#define DFF 512
#define TTW 64
#define NPI 8
#define NTOK 9
#define TILE_M 16

typedef __attribute__((ext_vector_type(8))) short short8;
typedef __attribute__((ext_vector_type(4))) float float4v;

__device__ __forceinline__ float bf16lo_f32(unsigned u) {
    union { unsigned u; float f; } v; v.u = u << 16;
    return v.f;
}
__device__ __forceinline__ float bf16hi_f32(unsigned u) {
    union { unsigned u; float f; } v; v.u = u & 0xffff0000u;
    return v.f;
}
__device__ __forceinline__ unsigned pk_bf16(float a, float b) {  // -> a | b<<16
    __hip_bfloat162 h = __float22bfloat162_rn(float2{a, b});
    union { __hip_bfloat162 h; unsigned u; } cv; cv.h = h;
    return cv.u;
}

// ==== prep: hf->bf16, W1 transpose, gamma-folded W2 transpose, C1/C2 vectors ====
// LN-fold: logits = rs*(h_raw @ (g.*W2)) - rs*mu*C1 + C2,
//   C1[t] = sum_k g[k]*W2[k][t],  C2[t] = b2[t] + sum_k be[k]*W2[k][t].
__global__ __launch_bounds__(256)
void prep_k(const float* __restrict__ hf, const float* __restrict__ W1,
            const float* __restrict__ W2, const float* __restrict__ gamma,
            const float* __restrict__ beta, const float* __restrict__ b2,
            unsigned short* __restrict__ hf2, unsigned short* __restrict__ w1t,
            unsigned short* __restrict__ w2g,
            float* __restrict__ C1, float* __restrict__ C2,
            int n_hf, int B_HF)
{
    __shared__ float tile[32][33];
    const int b = blockIdx.x, t = threadIdx.x;
    if (b < B_HF) {
        int i = (b * 256 + t) * 8;
        if (i < n_hf) {
            float4v v0 = *(const float4v*)(hf + i);
            float4v v1 = *(const float4v*)(hf + i + 4);
            uint4 o;
            o.x = pk_bf16(v0[0], v0[1]);
            o.y = pk_bf16(v0[2], v0[3]);
            o.z = pk_bf16(v1[0], v1[1]);
            o.w = pk_bf16(v1[2], v1[3]);
            *(uint4*)(hf2 + i) = o;
        }
    } else if (b < B_HF + 64) {
        const int tb = b - B_HF;            // W1 [128][512] -> w1t bf16 [512][128]
        const int r0 = (tb & 3) * 32, c0 = (tb >> 2) * 32;
        const int ty = t >> 3, tx = t & 7;
        *(float4v*)&tile[ty][tx * 4] = *(const float4v*)(W1 + (r0 + ty) * DFF + c0 + tx * 4);
        __syncthreads();
        uint2 o;
        o.x = pk_bf16(tile[tx * 4 + 0][ty], tile[tx * 4 + 1][ty]);
        o.y = pk_bf16(tile[tx * 4 + 2][ty], tile[tx * 4 + 3][ty]);
        *(uint2*)(w1t + (c0 + ty) * DIM + r0 + tx * 4) = o;
    } else if (b < B_HF + 96) {
        const int tb = b - B_HF - 64;       // W2 [512][64] -> w2g bf16 [64][512], *gamma[k]
        const int r0 = (tb & 15) * 32, c0 = (tb >> 4) * 32;
        const int ty = t >> 3, tx = t & 7;
        const float g = gamma[r0 + ty];     // k = r0 + ty
        float4v v = *(const float4v*)(W2 + (r0 + ty) * TTW + c0 + tx * 4);
        v[0] *= g; v[1] *= g; v[2] *= g; v[3] *= g;
        *(float4v*)&tile[ty][tx * 4] = v;
        __syncthreads();
        uint2 o;
        o.x = pk_bf16(tile[tx * 4 + 0][ty], tile[tx * 4 + 1][ty]);
        o.y = pk_bf16(tile[tx * 4 + 2][ty], tile[tx * 4 + 3][ty]);
        *(uint2*)(w2g + (c0 + ty) * DFF + r0 + tx * 4) = o;
    } else {
        // C1/C2: lanes 0..63, tt = t; k-loop is coalesced across lanes
        if (t < TTW) {
            float c1 = 0.f, c2 = 0.f;
            for (int k = 0; k < DFF; ++k) {
                float w = W2[k * TTW + t];
                c1 += gamma[k] * w;
                c2 += beta[k] * w;
            }
            C1[t] = c1;
            C2[t] = b2[t] + c2;
        }
    }
}

// ================= pool_k: gather + masked attention pooling ==================
// One hop per 32-lane group, no LDS, no barriers. Empirical occupancy law
// (R0-R6): pinned (256,N) -> VGPR cap ~256/N, REALIZED occ ~0.8*N waves/SIMD;
// UNPINNED realizes only ~0.4*cap. So pin (256,4): cap 64 >= ~55 demand,
// realized 3.2/SIMD instead of unpinned ~2.8.
__global__ __launch_bounds__(256, 4)
void pool_k(const unsigned short* __restrict__ hf2,
            const float* __restrict__ w_q,
            const int* __restrict__ pi,
            const int* __restrict__ stats,
            const int* __restrict__ po,
            uint2* apool,                   // [H][32] uint2 == bf16 [H][128]
            int H)
{
    const int t = threadIdx.x;
    const int g = t >> 5, l = t & 31;       // lane l owns dims 4l..4l+3
    const int hop = blockIdx.x * 8 + g;
    if (hop >= H) return;

    const float4v wq4 = *(const float4v*)(w_q + l * 4);
    const int4 p0 = *(const int4*)(pi + hop * NPI);
    const int4 p1 = *(const int4*)(pi + hop * NPI + 4);
    const int4 s0 = *(const int4*)(stats + hop * NPI);
    const int4 s1 = *(const int4*)(stats + hop * NPI + 4);
    const int ipo = po[hop];

    uint2 tu[NTOK];                         // 18 VGPRs; all 9 loads in flight
    tu[0] = *(const uint2*)(hf2 + (size_t)p0.x * DIM + l * 4);
    tu[1] = *(const uint2*)(hf2 + (size_t)p0.y * DIM + l * 4);
    tu[2] = *(const uint2*)(hf2 + (size_t)p0.z * DIM + l * 4);
    tu[3] = *(const uint2*)(hf2 + (size_t)p0.w * DIM + l * 4);
    tu[4] = *(const uint2*)(hf2 + (size_t)p1.x * DIM + l * 4);
    tu[5] = *(const uint2*)(hf2 + (size_t)p1.y * DIM + l * 4);
    tu[6] = *(const uint2*)(hf2 + (size_t)p1.z * DIM + l * 4);
    tu[7] = *(const uint2*)(hf2 + (size_t)p1.w * DIM + l * 4);
    tu[8] = *(const uint2*)(hf2 + (size_t)ipo * DIM + l * 4);

    const unsigned vm = (s0.x != -1 ? 1u   : 0u) | (s0.y != -1 ? 2u   : 0u)
                      | (s0.z != -1 ? 4u   : 0u) | (s0.w != -1 ? 8u   : 0u)
                      | (s1.x != -1 ? 16u  : 0u) | (s1.y != -1 ? 32u  : 0u)
                      | (s1.z != -1 ? 64u  : 0u) | (s1.w != -1 ? 128u : 0u)
                      | 256u;               // PO always valid

    float sc[NTOK];
    #pragma unroll
    for (int p = 0; p < NTOK; ++p) {        // unpack #1: dot only (transient)
        float x0 = bf16lo_f32(tu[p].x), x1 = bf16hi_f32(tu[p].x);
        float x2 = bf16lo_f32(tu[p].y), x3 = bf16hi_f32(tu[p].y);
        sc[p] = x0 * wq4[0] + x1 * wq4[1] + x2 * wq4[2] + x3 * wq4[3];
    }
    #pragma unroll
    for (int m = 1; m < 32; m <<= 1) {
        #pragma unroll
        for (int p = 0; p < NTOK; ++p) sc[p] += __shfl_xor(sc[p], m);
    }
    const float isd = 0.08838834764831845f; // 1/sqrt(128)
    float mx = -1e30f;
    #pragma unroll
    for (int p = 0; p < NTOK; ++p) {
        sc[p] = ((vm >> p) & 1u) ? sc[p] * isd : -1e30f;
        mx = fmaxf(mx, sc[p]);
    }
    float se = 0.f;
    #pragma unroll
    for (int p = 0; p < NTOK; ++p) { sc[p] = __expf(sc[p] - mx); se += sc[p]; }
    const float inv = 1.f / se;
    float a0 = 0.f, a1 = 0.f, a2 = 0.f, a3 = 0.f;
    #pragma unroll
    for (int p = 0; p < NTOK; ++p) {        // unpack #2: weighted sum
        const float a = sc[p] * inv;
        a0 += a * bf16lo_f32(tu[p].x);  a1 += a * bf16hi_f32(tu[p].x);
        a2 += a * bf16lo_f32(tu[p].y);  a3 += a * bf16hi_f32(tu[p].y);
    }
    uint2 o;
    o.x = pk_bf16(a0, a1);
    o.y = pk_bf16(a2, a3);
    apool[(size_t)hop * 32 + l] = o;        // 32 lanes x 8 B contiguous
}

// ========== mlp_k v2: TILE_M=16, GEMM1 (grouped acc) -> LN-fold -> full-K GEMM2 ==
// R6 measured: 102 us, MfmaUtil 7.3%, VALU 14%, HBM 5% -> pure latency at
// ~1.5 waves/SIMD (unpinned 0.4x law). v2: halve the tile so register peak
// fits the (256,3) pin cap (~85): acc reduced 64->16 by processing mt in two
// groups of 4 (bias/ReLU/pack after each group; only pk[8]=16 regs persist),
// bfr 32->16. Peak ~60-75 -> no spill, realized ~2.4 waves/SIMD (1.6x R6),
// per-block path halves, k-split barriers deleted (3 barriers total).
// Tripwire: WRITE_SIZE >> 25 MB = spill -> next round (256,2).
// apool aliases d_out: block reads only rows [hop0, hop0+16) (tail clamp
// H-1 stays inside the owning tail block), writes the same rows -> race-free.
__global__ __launch_bounds__(256, 3)
void mlp_k(const uint4* apool4,             // [H][16] uint4 == bf16 [H][128]
           const unsigned short* __restrict__ w1t,     // bf16 [512][128]
           const float* __restrict__ b1,
           const unsigned short* __restrict__ w2g,     // bf16 [64][512] (gamma-folded)
           const float* __restrict__ C1,
           const float* __restrict__ C2,
           float* out,
           int H)
{
    __shared__ __align__(16) unsigned short Apool[TILE_M][DIM + 8];   // 4352 B
    __shared__ __align__(16) unsigned short Hsm[TILE_M][DFF + 8];     // 16640 B
    __shared__ float part[16][4][2];                    // [row][wave][sum,ssq]
    __shared__ float2 mursm[TILE_M];                    // {mu, rs} per hop

    const int t    = threadIdx.x;
    const int lane = t & 63;
    const int w    = t >> 6;
    const int row  = lane & 15;
    const int quad = lane >> 4;
    const int hop0 = blockIdx.x * TILE_M;

    // -------- stage apool tile: 256 uint4 (4 KB), one per thread --------
    {
        int gr = hop0 + (t >> 4);
        if (gr >= H) gr = H - 1;
        uint4 v = apool4[(size_t)gr * 16 + (t & 15)];
        *(uint4*)&Apool[t >> 4][(t & 15) * 8] = v;
    }
    __syncthreads();

    // -------- GEMM1 in two mt-groups of 4; bias+ReLU+stats+pack per group ----
    short8 bfr[4];
    #pragma unroll
    for (int ks = 0; ks < 4; ++ks)
        bfr[ks] = *(const short8*)&Apool[row][ks * 32 + quad * 8];

    float sum = 0.f, ssq = 0.f;
    uint2 pk[8];
    #pragma unroll
    for (int gmt = 0; gmt < 2; ++gmt) {
        float4v acc4[4];
        #pragma unroll
        for (int m4 = 0; m4 < 4; ++m4)
            acc4[m4] = (float4v){0.f, 0.f, 0.f, 0.f};
        #pragma unroll
        for (int m4 = 0; m4 < 4; ++m4) {
            const int mt = gmt * 4 + m4;
            const unsigned short* wrow = w1t + (size_t)(mt * 64 + w * 16 + row) * DIM;
            #pragma unroll
            for (int ks = 0; ks < 4; ++ks) {
                short8 afr = *(const short8*)(wrow + ks * 32 + quad * 8);
                acc4[m4] = __builtin_amdgcn_mfma_f32_16x16x32_bf16(afr, bfr[ks], acc4[m4], 0, 0, 0);
            }
        }
        #pragma unroll
        for (int m4 = 0; m4 < 4; ++m4) {
            const int mt = gmt * 4 + m4;
            const int nb = mt * 64 + w * 16 + quad * 4;
            const float4v bias = *(const float4v*)(b1 + nb);
            float o0[4];
            #pragma unroll
            for (int r = 0; r < 4; ++r) {
                o0[r] = fmaxf(acc4[m4][r] + bias[r], 0.f);
                sum += o0[r];  ssq += o0[r] * o0[r];
            }
            pk[mt].x = pk_bf16(o0[0], o0[1]);
            pk[mt].y = pk_bf16(o0[2], o0[3]);
        }
    }
    // -------- LN stats reduce + publish pre-LN h to Hsm (one barrier) --------
    #pragma unroll
    for (int m = 16; m <= 32; m <<= 1) {       // reduce across the 4 quads
        sum += __shfl_xor(sum, m);  ssq += __shfl_xor(ssq, m);
    }
    if (lane < 16) {
        part[row][w][0] = sum;  part[row][w][1] = ssq;
    }
    #pragma unroll
    for (int mt = 0; mt < 8; ++mt)
        *(uint2*)&Hsm[row][mt * 64 + w * 16 + quad * 4] = pk[mt];
    __syncthreads();
    if (t < 16) {                              // wave 0, quad 0: row == t
        float S = 0.f, Q = 0.f;
        #pragma unroll
        for (int ww = 0; ww < 4; ++ww) { S += part[t][ww][0]; Q += part[t][ww][1]; }
        const float invn = 1.f / (float)DFF;
        float mu = S * invn;
        float rs = rsqrtf(Q * invn - mu * mu + 1e-5f);
        mursm[t] = float2{mu, rs};
    }
    // -------- GEMM2: full K=512, A=Hsm [hop][k] LDS, B=w2g [tt][k] global -----
    {
        float4v acc2 = (float4v){0.f, 0.f, 0.f, 0.f};
        const unsigned short* w2row = w2g + (size_t)(w * 16 + row) * DFF;
        #pragma unroll
        for (int ks = 0; ks < 16; ++ks) {
            const int k0 = ks * 32 + quad * 8;
            short8 bfr2 = *(const short8*)(w2row + k0);
            short8 afr2 = *(const short8*)&Hsm[row][k0];
            acc2 = __builtin_amdgcn_mfma_f32_16x16x32_bf16(afr2, bfr2, acc2, 0, 0, 0);
        }
        __syncthreads();                       // mursm visible to all waves
        // epilogue: LN applied algebraically: rs*(acc2 - mu*C1[tt]) + C2[tt]
        const int tt = w * 16 + row;
        const float c1v = C1[tt];
        const float c2v = C2[tt];
        #pragma unroll
        for (int r = 0; r < 4; ++r) {
            const int hl = quad * 4 + r;
            int hop = hop0 + hl;
            if (hop < H) {
                float2 mr = mursm[hl];         // {mu, rs}
                out[(size_t)hop * TTW + tt] = mr.y * (acc2[r] - mr.x * c1v) + c2v;
            }
        }
    }
}

extern "C" void kernel_launch(void* const* d_in, const int* in_sizes, int n_in,
                              void* d_out, int out_size, void* d_ws, size_t ws_size,
                              hipStream_t stream) {
    const float* hf    = (const float*)d_in[0];
    const float* w_q   = (const float*)d_in[1];
    const float* W1    = (const float*)d_in[2];
    const float* b1    = (const float*)d_in[3];
    const float* gamma = (const float*)d_in[4];
    const float* beta  = (const float*)d_in[5];
    const float* W2    = (const float*)d_in[6];
    const float* b2    = (const float*)d_in[7];
    const int* pi      = (const int*)d_in[8];
    const int* stats   = (const int*)d_in[9];
    const int* po      = (const int*)d_in[10];
    float* out         = (float*)d_out;

    const int n_hf = in_sizes[0];           // N_NODES*128
    const int H    = in_sizes[10];
    const int ntiles = (H + TILE_M - 1) / TILE_M;

    // ws layout: w1t 128KB | w2g 64KB | hf2 n_hf*2 | C1 256B | C2 256B
    char* ws = (char*)d_ws;
    unsigned short* w1t = (unsigned short*)ws;                       // 131072 B
    unsigned short* w2g = (unsigned short*)(ws + 131072);            // 65536 B
    unsigned short* hf2 = (unsigned short*)(ws + 196608);            // n_hf*2 B
    float* C1 = (float*)(ws + 196608 + (size_t)n_hf * 2);            // 256 B
    float* C2 = C1 + TTW;                                            // 256 B

    const int B_HF = (n_hf + 2047) / 2048;   // 8 elems/thread
    hipLaunchKernelGGL(prep_k, dim3(B_HF + 97), dim3(256), 0, stream,
                       hf, W1, W2, gamma, beta, b2, hf2, w1t, w2g, C1, C2, n_hf, B_HF);
    // apool (bf16 [H][128], H*256 B) aliases d_out (f32 [H][64], H*256 B):
    // pool_k fills it fully; each mlp_k block reads only its own tile before
    // overwriting those same rows with logits.
    hipLaunchKernelGGL(pool_k, dim3((H + 7) / 8), dim3(256), 0, stream,
                       hf2, w_q, pi, stats, po, (uint2*)d_out, H);
    hipLaunchKernelGGL(mlp_k, dim3(ntiles), dim3(256), 0, stream,
                       (const uint4*)d_out, w1t, b1, w2g, C1, C2, out, H);
}